// Round 2
// baseline (194.422 us; speedup 1.0000x reference)
//
#include <hip/hip_runtime.h>

#define NN 32
#define CC 256
#define KK 8192
#define PARTS 16
#define TPB 256
#define SLOTS 128
#define MAX_INIT (-100.0f)

typedef unsigned int uint32;

// monotone float -> uint key: unsigned compare order == float order
__device__ __forceinline__ uint32 fkey(float x) {
    uint32 b = __float_as_uint(x);
    return b ^ ((uint32)((int)b >> 31) | 0x80000000u);
}
__device__ __forceinline__ float funkey(uint32 k) {
    uint32 m = ((uint32)((int)(~k) >> 31)) | 0x80000000u;
    return __uint_as_float(k ^ m);
}

// ws layout: counts[(NN+1)*PARTS] floats at offset 0 (row NN = patch_count);
//            packed[NN*KK] bytes at offset 4096: (label & 15) | (valid ? 16 : 0)
__global__ __launch_bounds__(TPB) void prep_kernel(const int* __restrict__ labels,
                                                   const int* __restrict__ vm,
                                                   float* __restrict__ counts,
                                                   unsigned char* __restrict__ packed) {
    __shared__ float cnt[PARTS * TPB];
    const int t = threadIdx.x;
    const int b = blockIdx.x;
#pragma unroll
    for (int p = 0; p < PARTS; ++p) cnt[p * TPB + t] = 0.0f;
    __syncthreads();
    const int4* __restrict__ l4 = (const int4*)labels;
    if (b < NN) {
        const int4* __restrict__ v4 = (const int4*)(vm + (size_t)b * KK);
        uchar4* __restrict__ p4 = (uchar4*)(packed + (size_t)b * KK);
        for (int i = t; i < KK / 4; i += TPB) {
            int4 l = l4[i];
            int4 v = v4[i];
            uchar4 pb;
            pb.x = (unsigned char)((l.x & 15) | (v.x ? 16 : 0));
            pb.y = (unsigned char)((l.y & 15) | (v.y ? 16 : 0));
            pb.z = (unsigned char)((l.z & 15) | (v.z ? 16 : 0));
            pb.w = (unsigned char)((l.w & 15) | (v.w ? 16 : 0));
            p4[i] = pb;
            cnt[l.x * TPB + t] += v.x ? 1.0f : 0.0f;
            cnt[l.y * TPB + t] += v.y ? 1.0f : 0.0f;
            cnt[l.z * TPB + t] += v.z ? 1.0f : 0.0f;
            cnt[l.w * TPB + t] += v.w ? 1.0f : 0.0f;
        }
    } else {
        for (int i = t; i < KK / 4; i += TPB) {
            int4 l = l4[i];
            cnt[l.x * TPB + t] += 1.0f;
            cnt[l.y * TPB + t] += 1.0f;
            cnt[l.z * TPB + t] += 1.0f;
            cnt[l.w * TPB + t] += 1.0f;
        }
    }
    __syncthreads();
    for (int s = TPB / 2; s > 0; s >>= 1) {
        if (t < s) {
#pragma unroll
            for (int p = 0; p < PARTS; ++p) cnt[p * TPB + t] += cnt[p * TPB + t + s];
        }
        __syncthreads();
    }
    if (t < PARTS) counts[b * PARTS + t] = cnt[t * TPB];
}

// One block per (n,c) row. Per-part accumulators in LDS [part][slot],
// slot = t & 127. All accumulation via fire-and-forget LDS atomics
// (ds_add_f32 / ds_max_u32) -> no read-modify-write latency chains.
__global__ __launch_bounds__(TPB) void pool_kernel(const float* __restrict__ feats,
                                                   const unsigned char* __restrict__ packed,
                                                   const float* __restrict__ counts,
                                                   float* __restrict__ out) {
    __shared__ float ssum[PARTS * SLOTS];
    __shared__ uint32 smaxk[PARTS * SLOTS];
    const int t = threadIdx.x;
    const int b = blockIdx.x;          // b = n*256 + c
    const int n = b >> 8;
    const uint32 kinit = fkey(MAX_INIT);

    for (int i = t; i < PARTS * SLOTS; i += TPB) {
        ssum[i] = 0.0f;
        smaxk[i] = kinit;
    }
    __syncthreads();

    const float4* __restrict__ frow = (const float4*)(feats + (size_t)b * KK);
    const uchar4* __restrict__ prow = (const uchar4*)(packed + (size_t)n * KK);
    const int ts = t & (SLOTS - 1);

#define DO_ELEM(FV, PB)                                                                     \
    do {                                                                                    \
        int a_ = ((PB) & 15) * SLOTS + ts;                                                  \
        __hip_atomic_fetch_max(&smaxk[a_], fkey(FV), __ATOMIC_RELAXED,                      \
                               __HIP_MEMORY_SCOPE_WORKGROUP);                               \
        if ((PB) & 16)                                                                      \
            __hip_atomic_fetch_add(&ssum[a_], (FV), __ATOMIC_RELAXED,                       \
                                   __HIP_MEMORY_SCOPE_WORKGROUP);                           \
    } while (0)

#pragma unroll
    for (int iter = 0; iter < KK / 4 / TPB; ++iter) {
        const int i = iter * TPB + t;
        float4 f = frow[i];
        uchar4 pb = prow[i];
        DO_ELEM(f.x, pb.x);
        DO_ELEM(f.y, pb.y);
        DO_ELEM(f.z, pb.z);
        DO_ELEM(f.w, pb.w);
    }
#undef DO_ELEM
    __syncthreads();

    // Group g (16 threads, j = t&15) reduces part g over 128 slots.
    const int g = t >> 4;
    const int j = t & 15;
    float rs = 0.0f;
    uint32 rk = kinit;
#pragma unroll
    for (int i = 0; i < SLOTS / 16; ++i) {
        rs += ssum[g * SLOTS + j + 16 * i];
        rk = max(rk, smaxk[g * SLOTS + j + 16 * i]);
    }
#pragma unroll
    for (int m = 8; m >= 1; m >>= 1) {
        rs += __shfl_xor(rs, m, 64);
        rk = max(rk, (uint32)__shfl_xor((int)rk, m, 64));
    }
    if (j == 0) {
        float cntv = counts[n * PARTS + g];
        float pcv  = counts[NN * PARTS + g];
        float mean = rs / fmaxf(cntv, 1.0f);
        float mx   = (pcv > 0.0f) ? funkey(rk) : 0.0f;
        out[(size_t)b * PARTS + g] = mean + mx;
    }
}

extern "C" void kernel_launch(void* const* d_in, const int* in_sizes, int n_in,
                              void* d_out, int out_size, void* d_ws, size_t ws_size,
                              hipStream_t stream) {
    const float* feats  = (const float*)d_in[0];
    const int*   labels = (const int*)d_in[1];
    const int*   vm     = (const int*)d_in[2];
    float* out = (float*)d_out;
    float* counts = (float*)d_ws;
    unsigned char* packed = (unsigned char*)d_ws + 4096;

    prep_kernel<<<NN + 1, TPB, 0, stream>>>(labels, vm, counts, packed);
    pool_kernel<<<NN * CC, TPB, 0, stream>>>(feats, packed, counts, out);
}

// Round 3
// 103.920 us; speedup vs baseline: 1.8709x; 1.8709x over previous
//
#include <hip/hip_runtime.h>

#define NN 32
#define CC 256
#define KK 8192
#define PARTS 16
#define TPB 256
#define PADK 9216  // >= 8192 + 16*63 = 9200 (buckets padded to multiples of 64)
#define MAX_INIT (-100.0f)

typedef unsigned int uint32;
typedef unsigned short ushort16;

// ---------------------------------------------------------------------------
// ws layout (bytes):
//   0      : counts   float[(NN+1)*PARTS]   rows 0..31 = pooled_count[n][p], row 32 = patch_count[p]
//   4096   : poff     uint[PARTS+1]         padded bucket offsets (multiples of 64)
//   8192   : permbase ushort[PADK]          k | (isPad<<15); pads carry first-real k of their part
//   28672  : partOf   uchar[PADK]
//   40960  : vmperm   ushort[NN*PADK]       k | (valid<<15)  (valid=0 for pads)
// ---------------------------------------------------------------------------

// Single-block stable counting sort of labels into padded part buckets.
__global__ __launch_bounds__(TPB) void sort_kernel(const int* __restrict__ labels,
                                                   float* __restrict__ counts,
                                                   uint32* __restrict__ poff_g,
                                                   ushort16* __restrict__ permbase,
                                                   unsigned char* __restrict__ partOf) {
    __shared__ ushort16 lh[PARTS][TPB];    // per-thread histograms (max 32 each)
    __shared__ uint32 pexc[PARTS][TPB];    // exclusive prefix over threads, per part
    __shared__ uint32 wtot[PARTS][4];
    __shared__ uint32 s_off[PARTS + 1];
    __shared__ uint32 s_hist[PARTS];
    __shared__ ushort16 s_perm[PADK];
    const int t = threadIdx.x;
    const int CH = KK / TPB;  // 32
    const int w = t >> 6;

#pragma unroll
    for (int p = 0; p < PARTS; ++p) lh[p][t] = 0;
    __syncthreads();
    for (int i = 0; i < CH; ++i) {
        int p = labels[t * CH + i] & 15;
        lh[p][t]++;
    }
    __syncthreads();
    // parallel exclusive scan over the 256 thread-histograms, per part
    for (int p = 0; p < PARTS; ++p) {
        uint32 v = lh[p][t];
        uint32 inc = v;
#pragma unroll
        for (int s = 1; s < 64; s <<= 1) {
            uint32 o = __shfl_up(inc, s, 64);
            if ((t & 63) >= s) inc += o;
        }
        pexc[p][t] = inc - v;  // exclusive within wave
        if ((t & 63) == 63) wtot[p][w] = inc;
    }
    __syncthreads();
    for (int p = 0; p < PARTS; ++p) {
        uint32 base = 0;
        for (int ww = 0; ww < w; ++ww) base += wtot[p][ww];
        pexc[p][t] += base;
    }
    __syncthreads();
    if (t < PARTS) s_hist[t] = pexc[t][TPB - 1] + lh[t][TPB - 1];
    __syncthreads();
    if (t == 0) {
        uint32 off = 0;
        for (int p = 0; p < PARTS; ++p) {
            s_off[p] = off;
            off += (s_hist[p] + 63u) & ~63u;
            counts[NN * PARTS + p] = (float)s_hist[p];  // patch_count
        }
        s_off[PARTS] = off;
    }
    __syncthreads();
    // stable scatter (reuse lh as running per-thread counter)
#pragma unroll
    for (int p = 0; p < PARTS; ++p) lh[p][t] = 0;
    for (int i = 0; i < CH; ++i) {
        int k = t * CH + i;
        int p = labels[k] & 15;
        uint32 pos = s_off[p] + pexc[p][t] + lh[p][t];
        lh[p][t]++;
        s_perm[pos] = (ushort16)k;
    }
    __syncthreads();
    const uint32 end = s_off[PARTS];
    for (uint32 jp = t; jp < PADK; jp += TPB) {
        if (jp >= end) {
            permbase[jp] = 0;
            partOf[jp] = 0;
            continue;
        }
        int p = 0;
#pragma unroll
        for (int q = 1; q < PARTS; ++q) p += (jp >= s_off[q]) ? 1 : 0;
        ushort16 v;
        if (jp < s_off[p] + s_hist[p])
            v = s_perm[jp];  // real element
        else
            v = (ushort16)((s_hist[p] ? s_perm[s_off[p]] : 0) | 0x8000u);  // pad -> first real k
        permbase[jp] = v;
        partOf[jp] = (unsigned char)p;
    }
    if (t <= PARTS) poff_g[t] = s_off[t];
}

// Per-n: bake vm into the permuted side data and compute pooled_count[n][p].
__global__ __launch_bounds__(TPB) void side_kernel(const int* __restrict__ vm,
                                                   const uint32* __restrict__ poff_g,
                                                   const ushort16* __restrict__ permbase,
                                                   const unsigned char* __restrict__ partOf,
                                                   float* __restrict__ counts,
                                                   ushort16* __restrict__ vmperm) {
    __shared__ float cnt[PARTS * TPB];
    const int t = threadIdx.x;
    const int n = blockIdx.x;
#pragma unroll
    for (int p = 0; p < PARTS; ++p) cnt[p * TPB + t] = 0.0f;
    __syncthreads();
    const uint32 end = poff_g[PARTS];
    const int* __restrict__ vmn = vm + (size_t)n * KK;
    ushort16* __restrict__ vpn = vmperm + (size_t)n * PADK;
    for (uint32 jp = t; jp < end; jp += TPB) {
        uint32 u = permbase[jp];
        int p = partOf[jp];
        uint32 k = u & 0x1fffu;
        int valid = (u & 0x8000u) ? 0 : (vmn[k] ? 1 : 0);
        vpn[jp] = (ushort16)(k | (valid << 15));
        cnt[p * TPB + t] += (float)valid;
    }
    __syncthreads();
    for (int s = TPB / 2; s > 0; s >>= 1) {
        if (t < s) {
#pragma unroll
            for (int p = 0; p < PARTS; ++p) cnt[p * TPB + t] += cnt[p * TPB + t + s];
        }
        __syncthreads();
    }
    if (t < PARTS) counts[n * PARTS + t] = cnt[t * TPB];
}

// One block per (n,c) row: stage row in LDS, gather by sorted order,
// accumulate sum/max in registers (16 threads per part), shfl-reduce.
__global__ __launch_bounds__(TPB) void pool_kernel(const float* __restrict__ feats,
                                                   const ushort16* __restrict__ vmperm,
                                                   const uint32* __restrict__ poff_g,
                                                   const float* __restrict__ counts,
                                                   float* __restrict__ out) {
    __shared__ float row[KK];  // 32 KB
    const int t = threadIdx.x;
    const int b = blockIdx.x;  // n*256 + c
    const int n = b >> 8;
    const int g = t >> 4;      // part owned by this 16-thread group
    const int l = t & 15;

    const float4* __restrict__ f4 = (const float4*)(feats + (size_t)b * KK);
    float4* r4 = (float4*)row;
#pragma unroll
    for (int i = 0; i < KK / 4 / TPB; ++i) r4[i * TPB + t] = f4[i * TPB + t];

    const uint32 jbeg = poff_g[g];
    const uint32 jend = poff_g[g + 1];
    const ushort16* __restrict__ vpn = vmperm + (size_t)n * PADK;
    __syncthreads();

    float rs = 0.0f, rm = MAX_INIT;
#define ELEM(U)                                            \
    do {                                                   \
        uint32 u_ = (U);                                   \
        float f_ = row[u_ & 0x1fffu];                      \
        rm = fmaxf(rm, f_);                                \
        rs += (u_ & 0x8000u) ? f_ : 0.0f;                  \
    } while (0)
    for (uint32 jp = jbeg + l * 4; jp < jend; jp += 64) {
        uint2 d = *(const uint2*)(vpn + jp);
        ELEM(d.x & 0xffffu);
        ELEM(d.x >> 16);
        ELEM(d.y & 0xffffu);
        ELEM(d.y >> 16);
    }
#undef ELEM

#pragma unroll
    for (int m = 8; m >= 1; m >>= 1) {
        rs += __shfl_xor(rs, m, 64);
        rm = fmaxf(rm, __shfl_xor(rm, m, 64));
    }
    if (l == 0) {
        float cv = counts[n * PARTS + g];
        float pc = counts[NN * PARTS + g];
        out[(size_t)b * PARTS + g] = rs / fmaxf(cv, 1.0f) + (pc > 0.0f ? rm : 0.0f);
    }
}

extern "C" void kernel_launch(void* const* d_in, const int* in_sizes, int n_in,
                              void* d_out, int out_size, void* d_ws, size_t ws_size,
                              hipStream_t stream) {
    const float* feats  = (const float*)d_in[0];
    const int*   labels = (const int*)d_in[1];
    const int*   vm     = (const int*)d_in[2];
    float* out = (float*)d_out;

    float*         counts   = (float*)d_ws;
    uint32*        poff     = (uint32*)((char*)d_ws + 4096);
    ushort16*      permbase = (ushort16*)((char*)d_ws + 8192);
    unsigned char* partOf   = (unsigned char*)((char*)d_ws + 28672);
    ushort16*      vmperm   = (ushort16*)((char*)d_ws + 40960);

    sort_kernel<<<1, TPB, 0, stream>>>(labels, counts, poff, permbase, partOf);
    side_kernel<<<NN, TPB, 0, stream>>>(vm, poff, permbase, partOf, counts, vmperm);
    pool_kernel<<<NN * CC, TPB, 0, stream>>>(feats, vmperm, poff, counts, out);
}